// Round 8
// baseline (423.422 us; speedup 1.0000x reference)
//
#include <hip/hip_runtime.h>
#include <hip/hip_bf16.h>

// ABLATION ROUND: R2 kernel (best so far, 179us profiled) templated on V.
//  V=0 full (launched LAST -> correct d_out)
//  V=1 hot loads: every chunk re-reads chunk-0 addresses (L1/L2-hot)
//  V=2 no staging: loads+pack+ds_write skipped, frag LDS pre-zeroed
//  V=3 no MFMA: staging intact, MFMA+frag-reads skipped
//  V=4 floor: barriers + epilogue only
// All variants: same grid/block/LDS/launch_bounds, all write d_out fully.
// Per-dispatch rocprof rows give the phase decomposition.

#define CC 256
#define HH 128
#define WW 128
#define NT 169
#define PH 8
#define PW 16
#define QH 20
#define QW 28
#define CCH 32
#define NCH 8
#define CS 40
#define NPIXB (QH*QW)    // 560
#define NPIXA (PH*PW)    // 128
#define NUB (NPIXB*4)    // 2240
#define NUNIT (NUB + NPIXA*4)  // 2752
#define UPT 6
#define CHPLANE (HH*WW)
#define ABYTE (NPIXB*CS*2)     // 44800
#define KHALF 85
#define OSTRIDE 132

typedef __attribute__((ext_vector_type(8))) short bf16x8;
typedef __attribute__((ext_vector_type(4))) float f32x4;

union SMEM {
    unsigned short stage[NPIXB*CS + NPIXA*CS];   // 27520 shorts = 55040 B
    float outb[KHALF*OSTRIDE];
};

static __device__ __forceinline__ unsigned pk2(float a, float b) {
    unsigned x = __bfloat16_as_ushort(__float2bfloat16(a));
    unsigned y = __bfloat16_as_ushort(__float2bfloat16(b));
    return x | (y << 16);
}

template<int V>
__global__ __launch_bounds__(512, 2)
void lcT(const float* __restrict__ zt, const float* __restrict__ zt1,
         float* __restrict__ out) {
    __shared__ SMEM sm;
    char* smb = (char*)&sm;

    const int tid  = threadIdx.x;
    const int lane = tid & 63;
    const int wid  = tid >> 6;
    const int py0  = (wid >> 2) * 4;
    const int px0  = (wid & 3) * 4;

    const int bid = blockIdx.x;
    const int b   = bid & 7;
    const int t   = bid >> 3;
    const int h0  = (t >> 3) * PH;
    const int w0  = (t & 7) * PW;

    const bool doStage = (V != 2) && (V != 4);
    const bool doMfma  = (V != 3) && (V != 4);

    if (!doStage) {   // frag LDS must be defined for MFMA reads
        for (int i = tid; i < NPIXB*CS + NPIXA*CS; i += 512) sm.stage[i] = 0;
    }

    // ---- staging unit descriptors ----
    const float* src[UPT];
    int   dstB[UPT];
    bool  ex[UPT], pv[UPT];
#pragma unroll
    for (int v = 0; v < UPT; ++v) {
        const int ui = tid + v * 512;
        ex[v] = ui < NUNIT;
        int pix, oct, gy, gx, valid;
        const float* base;
        if (ui < NUB) {
            oct = ui / NPIXB;
            pix = ui - oct * NPIXB;
            const int qyi = pix / QW;
            const int qxi = pix - qyi * QW;
            gy = h0 + qyi - 6;
            gx = w0 + qxi - 6;
            valid = (gy >= 0) & (gy < HH) & (gx >= 0) & (gx < WW);
            base = zt1;
            dstB[v] = pix * (CS*2) + oct * 16;
        } else {
            const int u2 = ui - NUB;
            oct = u2 >> 7;
            pix = u2 & 127;
            gy = h0 + (pix >> 4);
            gx = w0 + (pix & 15);
            valid = 1;
            base = zt;
            dstB[v] = ABYTE + pix * (CS*2) + oct * 16;
        }
        pv[v] = valid;
        src[v] = base + (((b * CC + oct * 8) * HH + (valid ? gy : 0)) * WW + (valid ? gx : 0));
    }

    // ---- fragment LDS byte offsets ----
    const int nlo = lane & 3, nhi = (lane >> 2) & 3, oo = lane >> 4;
    int boff[16];
#pragma unroll
    for (int qi = 0; qi < 16; ++qi) {
        const int qyL = py0 + (qi >> 2) * 4 + nhi;
        const int qxL = px0 + (qi & 3) * 4 + nlo;
        boff[qi] = (qyL * QW + qxL) * (CS*2) + oo * 16;
    }
    const int pixA = (py0 + nhi) * PW + px0 + nlo;
    const int aoff = ABYTE + pixA * (CS*2) + oo * 16;

    f32x4 acc[16];
#pragma unroll
    for (int qi = 0; qi < 16; ++qi) acc[qi] = (f32x4){0.f, 0.f, 0.f, 0.f};

    float pf[UPT][8];
    if (doStage) {
#pragma unroll
        for (int v = 0; v < UPT; ++v) {
            const bool ld = ex[v] && pv[v];
#pragma unroll
            for (int j = 0; j < 8; ++j) pf[v][j] = ld ? src[v][j * CHPLANE] : 0.f;
            if (V != 1) src[v] += CCH * CHPLANE;
        }
    }
    __syncthreads();

    for (int kc = 0; kc < NCH; ++kc) {
        if (doStage) {
#pragma unroll
            for (int v = 0; v < UPT; ++v) {
                if (ex[v]) {
                    uint4 q;
                    q.x = pk2(pf[v][0], pf[v][1]);
                    q.y = pk2(pf[v][2], pf[v][3]);
                    q.z = pk2(pf[v][4], pf[v][5]);
                    q.w = pk2(pf[v][6], pf[v][7]);
                    *(uint4*)(smb + dstB[v]) = q;
                }
            }
            if (kc + 1 < NCH) {
#pragma unroll
                for (int v = 0; v < UPT; ++v) {
                    const bool ld = ex[v] && pv[v];
#pragma unroll
                    for (int j = 0; j < 8; ++j) pf[v][j] = ld ? src[v][j * CHPLANE] : 0.f;
                    if (V != 1) src[v] += CCH * CHPLANE;
                }
            }
        }
        __syncthreads();

        if (doMfma) {
            const bf16x8 af = *(const bf16x8*)(smb + aoff);
#pragma unroll
            for (int qi = 0; qi < 16; ++qi) {
                const bf16x8 bfr = *(const bf16x8*)(smb + boff[qi]);
                acc[qi] = __builtin_amdgcn_mfma_f32_16x16x32_bf16(af, bfr, acc[qi], 0, 0, 0);
            }
        }
        __syncthreads();
    }

    // ---- epilogue (identical in all variants) ----
    const int psb = (py0 + oo) * PW + px0;
#pragma unroll 1
    for (int pass = 0; pass < 2; ++pass) {
        const int kb = pass * KHALF;
        const int nk = pass ? (NT - KHALF) : KHALF;
#pragma unroll
        for (int qi = 0; qi < 16; ++qi) {
            const int di = 4 * (qi >> 2) + nhi - oo;
            const bool diok = (unsigned)di <= 12u;
            const int dib = di * 13;
#pragma unroll
            for (int r = 0; r < 4; ++r) {
                const int dj = 4 * (qi & 3) + nlo - r;
                const int k  = dib + dj;
                if (diok && (unsigned)dj <= 12u && k >= kb && k < kb + nk)
                    sm.outb[(k - kb) * OSTRIDE + psb + r] = acc[qi][r] * 0.0625f;
            }
        }
        __syncthreads();
        const int total4 = nk * 32;
        for (int i = tid; i < total4; i += 512) {
            const int row = i >> 5, j = i & 31;
            const float4 val = *(const float4*)&sm.outb[row * OSTRIDE + j * 4];
            float* dst = out + (((b * NT + kb + row) * HH + h0 + (j >> 2)) * WW
                                + w0 + (j & 3) * 4);
            *(float4*)dst = val;
        }
        __syncthreads();
    }
}

extern "C" void kernel_launch(void* const* d_in, const int* in_sizes, int n_in,
                              void* d_out, int out_size, void* d_ws, size_t ws_size,
                              hipStream_t stream) {
    const float* zt  = (const float*)d_in[0];
    const float* zt1 = (const float*)d_in[1];
    float* out = (float*)d_out;
    // Ablation: floor, no-MFMA, no-staging, hot-loads, then FULL last
    // (stream order guarantees the correct variant's writes win).
    lcT<4><<<dim3(1024), dim3(512), 0, stream>>>(zt, zt1, out);
    lcT<3><<<dim3(1024), dim3(512), 0, stream>>>(zt, zt1, out);
    lcT<2><<<dim3(1024), dim3(512), 0, stream>>>(zt, zt1, out);
    lcT<1><<<dim3(1024), dim3(512), 0, stream>>>(zt, zt1, out);
    lcT<0><<<dim3(1024), dim3(512), 0, stream>>>(zt, zt1, out);
}

// Round 9
// 148.326 us; speedup vs baseline: 2.8547x; 2.8547x over previous
//
#include <hip/hip_runtime.h>
#include <hip/hip_bf16.h>

// LocalCorrelation, round 9: layout-first.
// K1: z_t1 fp32 [B,C,H,W] -> bf16 [B,H,W,C] in d_ws (LDS-tiled transpose).
// K2: R2-verified MFMA geometry; B staged by global_load_lds of contiguous
//     64-B px-slices from the HWC buffer (no B pack phase); A staged per
//     chunk from fp32 z_t via coalesced loads + tiny LDS pack.
// Swizzle (rule 21): LDS dest linear, SOURCE slot pre-swizzled by
// slot^((px>>1)&3), frag READ applies the same XOR -> 2-way max conflicts.

#define CHPL 16384
#define NT 169
#define KHALF 85
#define OSTRIDE 132
#define BFRAG 35840                 // 560 px * 64 B
#define AFRAG_OFF (2*BFRAG)         // 71680
#define SMTOT (AFRAG_OFF + 8192)    // 79872 -> 2 blocks/CU

typedef __attribute__((ext_vector_type(8))) short bf16x8;
typedef __attribute__((ext_vector_type(4))) float f32x4;
typedef unsigned int u32;
typedef unsigned short u16;

static __device__ __forceinline__ u32 pk2(float a, float b) {
    __hip_bfloat162 h = __float22bfloat162_rn(make_float2(a, b));
    union { __hip_bfloat162 h2; u32 u; } c; c.h2 = h; return c.u;
}

// ---------- K1: cast + transpose z_t1 -> bf16 HWC ----------
__global__ __launch_bounds__(256)
void lc_tr(const float* __restrict__ zt1, void* __restrict__ ws) {
    __shared__ float ld[64][68];    // row stride 272 B (16-B aligned)
    const int tid = threadIdx.x, bid = blockIdx.x;
    const int cb = bid & 3, wb = (bid >> 2) & 1;
    const int h = (bid >> 3) & 127, b = bid >> 10;
    if (bid == 0 && tid < 128) ((u32*)ws)[tid] = 0u;   // 512-B zero page
    const int c0 = cb * 64, w0 = wb * 64;
#pragma unroll
    for (int k = 0; k < 4; ++k) {
        const int u = tid + k * 256, ch = u >> 4, seg = u & 15;
        const float4 v = *(const float4*)(zt1 + ((size_t)(b * 256 + c0 + ch)) * CHPL
                                          + h * 128 + w0 + seg * 4);
        *(float4*)&ld[ch][seg * 4] = v;
    }
    __syncthreads();
    const int px = tid >> 2, part = tid & 3;
    u32 r[8];
#pragma unroll
    for (int j = 0; j < 8; ++j)
        r[j] = pk2(ld[part * 16 + 2 * j][px], ld[part * 16 + 2 * j + 1][px]);
    u16* dst = (u16*)((char*)ws + 512)
               + ((size_t)(b * 16384 + h * 128 + w0 + px)) * 256 + c0 + part * 16;
    *(uint4*)dst = make_uint4(r[0], r[1], r[2], r[3]);
    *(uint4*)(dst + 8) = make_uint4(r[4], r[5], r[6], r[7]);
}

// ---------- K2: correlation ----------
__global__ __launch_bounds__(512, 4)
void lc9(const float* __restrict__ zt, const void* __restrict__ ws,
         float* __restrict__ out) {
    __shared__ union { char raw[SMTOT]; float outb[KHALF * OSTRIDE]; } sm;
    char* smb = sm.raw;
    const int tid = threadIdx.x, lane = tid & 63, wid = tid >> 6;
    const int bid = blockIdx.x;
    const int b = bid & 7, t = bid >> 3;              // one batch per XCD
    const int h0 = (t >> 3) * 8, w0 = (t & 7) * 16;
    const int py0 = (wid >> 2) * 4, px0 = (wid & 3) * 4;
    const int nlo = lane & 3, nhi = (lane >> 2) & 3, oo = lane >> 4;

    const u16* zw = (const u16*)((const char*)ws + 512);
    const char* zpg = (const char*)ws;                // 512 B of zeros

    // ---- B-DMA descriptors: waves 0-6 x 5 instrs = 35 x 64 lanes = 2240 units
    const char* bsrc[5]; int badv[5]; int bdst[5];
    if (wid < 7) {
#pragma unroll
        for (int i = 0; i < 5; ++i) {
            const int I = wid * 5 + i;
            const int g = I * 64 + lane;              // unit < 2240
            const int px = g >> 2, slot = g & 3;
            const int qy = px / 28, qx = px % 28;
            const int gy = h0 + qy - 6, gx = w0 + qx - 6;
            const bool val = (gy >= 0) && (gy < 128) && (gx >= 0) && (gx < 128);
            const int ss = slot ^ ((px >> 1) & 3);    // inverse-swizzled source
            bsrc[i] = val ? (const char*)(zw + ((size_t)(b * 16384 + gy * 128 + gx)) * 256
                                          + ss * 8)
                          : zpg;
            badv[i] = val ? 64 : 0;                   // +32 ch (bf16) per chunk
            bdst[i] = I * 1024;                       // wave-uniform LDS base
        }
    }

#define BISSUE(PAR) if (wid < 7) { _Pragma("unroll")                           \
    for (int i = 0; i < 5; ++i) {                                              \
        __builtin_amdgcn_global_load_lds(                                      \
            (const __attribute__((address_space(1))) void*)bsrc[i],            \
            (__attribute__((address_space(3))) void*)(smb + (PAR)*BFRAG + bdst[i]), \
            16, 0, 0);                                                         \
        bsrc[i] += badv[i]; } }

    // ---- A staging: thread = (oct, pxA); coalesced 256-B runs from fp32 z_t
    const int octA = tid >> 7, pxu = tid & 127;
    const float* asrc = zt + ((size_t)(b * 256 + octA * 8)) * CHPL
                        + (h0 + (pxu >> 4)) * 128 + w0 + (pxu & 15);
    const int awoff = AFRAG_OFF + pxu * 64 + ((octA ^ ((pxu >> 1) & 3)) << 4);
    float pfA[2][8];

#define AISSUE(KC, PAR) { _Pragma("unroll")                                    \
    for (int e = 0; e < 8; ++e)                                                \
        pfA[PAR][e] = asrc[((size_t)((KC) * 32 + e)) * CHPL]; }

#define APACK(PAR) { uint4 q;                                                  \
    q.x = pk2(pfA[PAR][0], pfA[PAR][1]); q.y = pk2(pfA[PAR][2], pfA[PAR][3]);  \
    q.z = pk2(pfA[PAR][4], pfA[PAR][5]); q.w = pk2(pfA[PAR][6], pfA[PAR][7]);  \
    *(uint4*)(smb + awoff) = q; }

    // ---- MFMA frag offsets (R2-verified geometry + slot XOR) ----
    int boff[16];
#pragma unroll
    for (int qi = 0; qi < 16; ++qi) {
        const int px = (py0 + (qi >> 2) * 4 + nhi) * 28 + (px0 + (qi & 3) * 4 + nlo);
        boff[qi] = px * 64 + ((oo ^ ((px >> 1) & 3)) << 4);
    }
    const int pxm = (py0 + nhi) * 16 + px0 + nlo;
    const int aoff = AFRAG_OFF + pxm * 64 + ((oo ^ ((pxm >> 1) & 3)) << 4);

    f32x4 acc[16];
#pragma unroll
    for (int qi = 0; qi < 16; ++qi) acc[qi] = (f32x4){0.f, 0.f, 0.f, 0.f};

    // ---- main loop: 8 chunks of 32 ch, 2 barriers/chunk, full-chunk flight
    BISSUE(0) AISSUE(0, 0)
#pragma unroll
    for (int kc = 0; kc < 8; ++kc) {
        // c+d: own loads (B[kc] DMA + A[kc] regs) landed, then barrier
        asm volatile("s_waitcnt vmcnt(0)\n\ts_barrier" ::: "memory");
        // buf[(kc+1)&1] free (all waves finished MFMA kc-1) -> refill now;
        // loads fly across pack + barrier + MFMA of this chunk
        if (kc < 7) { BISSUE((kc + 1) & 1) AISSUE(kc + 1, (kc + 1) & 1) }
        APACK(kc & 1)
        asm volatile("s_waitcnt lgkmcnt(0)\n\ts_barrier" ::: "memory");
        const char* fb = smb + (kc & 1) * BFRAG;
        const bf16x8 af = *(const bf16x8*)(smb + aoff);
#pragma unroll
        for (int qi = 0; qi < 16; ++qi) {
            const bf16x8 bfr = *(const bf16x8*)(fb + boff[qi]);
            acc[qi] = __builtin_amdgcn_mfma_f32_16x16x32_bf16(af, bfr, acc[qi], 0, 0, 0);
        }
    }
    __syncthreads();   // MFMA frag reads done before outb aliases LDS

    // ---- epilogue (R2-verified, verbatim) ----
    const int psb = (py0 + oo) * 16 + px0;
#pragma unroll 1
    for (int pass = 0; pass < 2; ++pass) {
        const int kb = pass * KHALF;
        const int nk = pass ? (NT - KHALF) : KHALF;   // 85 / 84
#pragma unroll
        for (int qi = 0; qi < 16; ++qi) {
            const int di = 4 * (qi >> 2) + nhi - oo;
            const bool diok = (unsigned)di <= 12u;
            const int dib = di * 13;
#pragma unroll
            for (int r = 0; r < 4; ++r) {
                const int dj = 4 * (qi & 3) + nlo - r;
                const int k  = dib + dj;
                if (diok && (unsigned)dj <= 12u && k >= kb && k < kb + nk)
                    sm.outb[(k - kb) * OSTRIDE + psb + r] = acc[qi][r] * 0.0625f;
            }
        }
        __syncthreads();
        const int total4 = nk * 32;
        for (int i = tid; i < total4; i += 512) {
            const int row = i >> 5, j = i & 31;
            const float4 val = *(const float4*)&sm.outb[row * OSTRIDE + j * 4];
            float* dst = out + (((size_t)(b * NT + kb + row) * 128 + h0 + (j >> 2)) * 128
                                + w0 + (j & 3) * 4);
            *(float4*)dst = val;
        }
        __syncthreads();
    }
}

extern "C" void kernel_launch(void* const* d_in, const int* in_sizes, int n_in,
                              void* d_out, int out_size, void* d_ws, size_t ws_size,
                              hipStream_t stream) {
    const float* zt  = (const float*)d_in[0];
    const float* zt1 = (const float*)d_in[1];
    float* out = (float*)d_out;
    lc_tr<<<dim3(8192), dim3(256), 0, stream>>>(zt1, d_ws);
    lc9<<<dim3(1024), dim3(512), 0, stream>>>(zt, d_ws, out);
}